// Round 4
// baseline (1571.370 us; speedup 1.0000x reference)
//
#include <hip/hip_runtime.h>
#include <hip/hip_fp16.h>

// W8A16 GEMM: out[m,n] = (sum_k x[m,k]*w[n,k]) * scale[n] + bias[n]
// M=8192, K=4096, N=11008.
// Locked harness model (from absmax bit-pattern forensics r1-r3):
//   x: fp16 upcast to FLOAT32 [M,K]   (134 MB)
//   W: int8 widened to INT32  [N,K]   (180 MB)
//   scale, bias: float32 [N]
//   out: FLOAT32 [M,N]                (360 MB)
// Strategy: pre-convert x and W to fp16 in ws (both conversions EXACT),
// f16-MFMA 128x128 GEMM (m97 lineage), fp32 epilogue with scale+bias.

#define M_DIM 8192
#define K_DIM 4096
#define N_DIM 11008
#define TM 128
#define TN 128
#define BK 64
#define BKP 72  // padded LDS row stride (elems); 144 B rows, 16B-aligned frags

typedef __attribute__((ext_vector_type(8))) _Float16 half8;  // 4 VGPRs
typedef __attribute__((ext_vector_type(4))) float floatx4;   // MFMA acc

union Pack16 { int4 i4; unsigned short u[8]; _Float16 h[8]; };

// ---------------- probe: widened int32 weights vs raw int8 bytes ----------------
__global__ void init_flags(unsigned int* f) { f[0] = 0u; }

__global__ __launch_bounds__(256) void probe_w(const int* __restrict__ W,
                                               unsigned int* __restrict__ f) {
    const size_t i0 = (size_t)blockIdx.x * 256 + threadIdx.x;
    const size_t stride = (size_t)gridDim.x * 256;
    int bad = 0;
    for (size_t i = i0; i < (size_t)(1u << 20); i += stride) {  // 4MB, in-bounds either way
        int w = W[i];
        if (w > 127 || w < -127) bad = 1;
    }
    if (bad) atomicOr(f, 1u);
}

// ---------------- x: fp32 -> fp16 (exact: values originate as fp16) ----------------
__global__ __launch_bounds__(256) void convert_x(const float* __restrict__ Xf,
                                                 unsigned short* __restrict__ Xh) {
    const size_t i = ((size_t)blockIdx.x * 256 + threadIdx.x) * 8;
    float4 a = *(const float4*)(Xf + i);
    float4 b = *(const float4*)(Xf + i + 4);
    Pack16 p;
    p.h[0] = (_Float16)a.x; p.h[1] = (_Float16)a.y;
    p.h[2] = (_Float16)a.z; p.h[3] = (_Float16)a.w;
    p.h[4] = (_Float16)b.x; p.h[5] = (_Float16)b.y;
    p.h[6] = (_Float16)b.z; p.h[7] = (_Float16)b.w;
    *(int4*)(Xh + i) = p.i4;
}

// ---------------- W: int32 (or raw int8 per flag) -> fp16 (exact, |v|<=127) ----------------
__global__ __launch_bounds__(256) void convert_w(const void* __restrict__ Wraw,
                                                 unsigned short* __restrict__ Wh,
                                                 const unsigned int* __restrict__ f) {
    const bool w8 = f[0] != 0u;
    const size_t i = ((size_t)blockIdx.x * 256 + threadIdx.x) * 8;  // weight index
    int v[8];
    if (w8) {
        int2 b = *(const int2*)((const char*)Wraw + i);
#pragma unroll
        for (int j = 0; j < 4; ++j)
            v[j] = (int)(signed char)(unsigned char)((((unsigned)b.x) >> (8 * j)) & 0xFFu);
#pragma unroll
        for (int j = 0; j < 4; ++j)
            v[4 + j] = (int)(signed char)(unsigned char)((((unsigned)b.y) >> (8 * j)) & 0xFFu);
    } else {
        const int4* src = (const int4*)((const int*)Wraw + i);
        int4 w0 = src[0], w1 = src[1];
        v[0] = w0.x; v[1] = w0.y; v[2] = w0.z; v[3] = w0.w;
        v[4] = w1.x; v[5] = w1.y; v[6] = w1.z; v[7] = w1.w;
    }
    Pack16 p;
#pragma unroll
    for (int j = 0; j < 8; ++j) p.h[j] = (_Float16)v[j];
    *(int4*)(Wh + i) = p.i4;
}

// ---------------- GEMM: f16 MFMA, fp32 out ----------------
template <bool XPRE, bool WPRE>
__global__ __launch_bounds__(256) void w8a16_gemm(
    const float* __restrict__ Xf, const unsigned short* __restrict__ Xh,
    const int* __restrict__ Wi, const unsigned short* __restrict__ Wh,
    const float* __restrict__ scale, const float* __restrict__ bias,
    float* __restrict__ Out)
{
    __shared__ unsigned short As[TM * BKP];  // 18 KB
    __shared__ unsigned short Bs[TN * BKP];  // 18 KB

    const int t = threadIdx.x;
    const int lane = t & 63;
    const int wave = t >> 6;
    const int tileM = blockIdx.y * TM;
    const int tileN = blockIdx.x * TN;
    const int wm = (wave & 1) * 64;   // 2x2 wave grid, each wave 64x64
    const int wn = (wave >> 1) * 64;
    const int fr = lane & 15;         // fragment free index (A-row / B-col)
    const int fk = (lane >> 4) * 8;   // fragment k offset (quad*8)

    floatx4 acc[4][4];
#pragma unroll
    for (int mi = 0; mi < 4; ++mi)
#pragma unroll
        for (int ni = 0; ni < 4; ++ni) acc[mi][ni] = (floatx4){0.f, 0.f, 0.f, 0.f};

    for (int k0 = 0; k0 < K_DIM; k0 += BK) {
#pragma unroll
        for (int it = 0; it < 4; ++it) {
            const int c = it * 256 + t;  // [0,1024): row c>>3, col8 c&7
            const int r = c >> 3;
            const int q = c & 7;
            // ---- A ----
            if (XPRE) {
                *(int4*)(As + r * BKP + q * 8) =
                    *(const int4*)(Xh + (size_t)(tileM + r) * K_DIM + k0 + q * 8);
            } else {
                const float* s = Xf + (size_t)(tileM + r) * K_DIM + k0 + q * 8;
                float4 x0 = ((const float4*)s)[0];
                float4 x1 = ((const float4*)s)[1];
                Pack16 p;
                p.h[0] = (_Float16)x0.x; p.h[1] = (_Float16)x0.y;
                p.h[2] = (_Float16)x0.z; p.h[3] = (_Float16)x0.w;
                p.h[4] = (_Float16)x1.x; p.h[5] = (_Float16)x1.y;
                p.h[6] = (_Float16)x1.z; p.h[7] = (_Float16)x1.w;
                *(int4*)(As + r * BKP + q * 8) = p.i4;
            }
            // ---- B ----
            if (WPRE) {
                *(int4*)(Bs + r * BKP + q * 8) =
                    *(const int4*)(Wh + (size_t)(tileN + r) * K_DIM + k0 + q * 8);
            } else {
                const int* s = Wi + (size_t)(tileN + r) * K_DIM + k0 + q * 8;
                int4 w0 = ((const int4*)s)[0];
                int4 w1 = ((const int4*)s)[1];
                Pack16 p;
                p.h[0] = (_Float16)w0.x; p.h[1] = (_Float16)w0.y;
                p.h[2] = (_Float16)w0.z; p.h[3] = (_Float16)w0.w;
                p.h[4] = (_Float16)w1.x; p.h[5] = (_Float16)w1.y;
                p.h[6] = (_Float16)w1.z; p.h[7] = (_Float16)w1.w;
                *(int4*)(Bs + r * BKP + q * 8) = p.i4;
            }
        }
        __syncthreads();
#pragma unroll
        for (int kh = 0; kh < 2; ++kh) {
            half8 a[4], b[4];
#pragma unroll
            for (int i = 0; i < 4; ++i)
                a[i] = *(const half8*)(const void*)(As + (wm + i * 16 + fr) * BKP + kh * 32 + fk);
#pragma unroll
            for (int i = 0; i < 4; ++i)
                b[i] = *(const half8*)(const void*)(Bs + (wn + i * 16 + fr) * BKP + kh * 32 + fk);
#pragma unroll
            for (int mi = 0; mi < 4; ++mi)
#pragma unroll
                for (int ni = 0; ni < 4; ++ni)
                    acc[mi][ni] = __builtin_amdgcn_mfma_f32_16x16x32_f16(
                        a[mi], b[ni], acc[mi][ni], 0, 0, 0);
        }
        __syncthreads();
    }

    // C/D layout: col=lane&15, row=(lane>>4)*4+reg (m89/m91-verified)
    const int rbase = (lane >> 4) * 4;
#pragma unroll
    for (int ni = 0; ni < 4; ++ni) {
        const int n = tileN + wn + ni * 16 + fr;
        const float s = scale[n];
        const float bz = bias[n];
#pragma unroll
        for (int mi = 0; mi < 4; ++mi) {
            const int m = tileM + wm + mi * 16 + rbase;
#pragma unroll
            for (int r = 0; r < 4; ++r)
                Out[(size_t)(m + r) * N_DIM + n] = acc[mi][ni][r] * s + bz;
        }
    }
}

extern "C" void kernel_launch(void* const* d_in, const int* in_sizes, int n_in,
                              void* d_out, int out_size, void* d_ws, size_t ws_size,
                              hipStream_t stream) {
    // --- resolve inputs BY SIZE (robust to pytree vs insertion ordering) ---
    const long long SZ_X = (long long)M_DIM * K_DIM;  // 33,554,432
    const long long SZ_W = (long long)N_DIM * K_DIM;  // 45,088,768
    const void *pX = nullptr, *pW = nullptr, *pS = nullptr, *pB = nullptr;
    int smallIdx[8];
    int nSmall = 0;
    for (int i = 0; i < n_in; ++i) {
        long long s = in_sizes[i];
        if (s == SZ_X && !pX) pX = d_in[i];
        else if (s == SZ_W && !pW) pW = d_in[i];
        else if (s == (long long)N_DIM && nSmall < 8) smallIdx[nSmall++] = i;
    }
    if (nSmall == 2) {
        // weight_scale is index 2 in BOTH insertion order (x,W,scale,bias)
        // and alphabetical order (bias,W,scale,x).
        if (smallIdx[0] == 2)      { pS = d_in[2]; pB = d_in[smallIdx[1]]; }
        else if (smallIdx[1] == 2) { pS = d_in[2]; pB = d_in[smallIdx[0]]; }
        else                       { pS = d_in[smallIdx[0]]; pB = d_in[smallIdx[1]]; }
    }
    if (!pX || !pW || !pS || !pB) { pX = d_in[0]; pW = d_in[1]; pS = d_in[2]; pB = d_in[3]; }

    const float* Xf = (const float*)pX;
    const int* Wi = (const int*)pW;
    const float* scale = (const float*)pS;
    const float* bias = (const float*)pB;
    float* Out = (float*)d_out;

    dim3 grid(N_DIM / TN, M_DIM / TM);  // 86 x 64, exact cover
    const size_t OFF = 256;
    const size_t XH_BYTES = (size_t)SZ_X * 2;  // 67 MB fp16 x
    const size_t WH_BYTES = (size_t)SZ_W * 2;  // 90 MB fp16 w

    if (ws_size >= OFF + XH_BYTES + WH_BYTES + 64) {
        unsigned int* flags = (unsigned int*)d_ws;
        unsigned short* Xh = (unsigned short*)((char*)d_ws + OFF);
        unsigned short* Wh = (unsigned short*)((char*)d_ws + OFF + XH_BYTES);
        init_flags<<<1, 1, 0, stream>>>(flags);
        probe_w<<<256, 256, 0, stream>>>(Wi, flags);
        convert_x<<<(int)(SZ_X / 8 / 256), 256, 0, stream>>>(Xf, Xh);
        convert_w<<<(int)(SZ_W / 8 / 256), 256, 0, stream>>>(pW, Wh, flags);
        w8a16_gemm<true, true><<<grid, 256, 0, stream>>>(Xf, Xh, Wi, Wh, scale, bias, Out);
    } else if (ws_size >= OFF + WH_BYTES + 64) {
        unsigned int* flags = (unsigned int*)d_ws;
        unsigned short* Wh = (unsigned short*)((char*)d_ws + OFF);
        init_flags<<<1, 1, 0, stream>>>(flags);
        probe_w<<<256, 256, 0, stream>>>(Wi, flags);
        convert_w<<<(int)(SZ_W / 8 / 256), 256, 0, stream>>>(pW, Wh, flags);
        w8a16_gemm<false, true><<<grid, 256, 0, stream>>>(Xf, nullptr, Wi, Wh, scale, bias, Out);
    } else {
        // Inline-convert both (assumes widened int32 weights per harness doc).
        w8a16_gemm<false, false><<<grid, 256, 0, stream>>>(Xf, nullptr, Wi, nullptr, scale, bias, Out);
    }
}